// Round 11
// baseline (737.858 us; speedup 1.0000x reference)
//
#include <hip/hip_runtime.h>
#include <hip/hip_bf16.h>

typedef unsigned short u16;
typedef unsigned int u32;
using bf16x8 = __attribute__((ext_vector_type(8))) short;
using f32x4  = __attribute__((ext_vector_type(4))) float;

#define LDA   136   // 128 + 8 pad
#define SLOTS 8
#define NROWS 48

__device__ __forceinline__ u32 pk2bf(float a, float b) {
  u32 r;
  asm("v_cvt_pk_bf16_f32 %0, %1, %2" : "=v"(r) : "v"(a), "v"(b));
  return r;
}
__device__ __forceinline__ u16 f2bf(float f) { return (u16)pk2bf(f, f); }
__device__ __forceinline__ float bf2f(u16 h) {
  union { u32 u; float f; } v; v.u = ((u32)h) << 16;
  return v.f;
}
__device__ __forceinline__ float2 bf2x2(u32 u) {
  union { u32 u; float f; } a, b; a.u = u << 16; b.u = u & 0xffff0000u;
  return make_float2(a.f, b.f);
}

#if __has_builtin(__builtin_amdgcn_exp2f)
#define EXP2F(x) __builtin_amdgcn_exp2f(x)
#else
#define EXP2F(x) exp2f(x)
#endif

#define MFMA32(a, b, c) __builtin_amdgcn_mfma_f32_16x16x32_bf16(a, b, c, 0, 0, 0)

// tanh-form GELU (validated R3-R10: absmax stays 0.0625)
__device__ __forceinline__ float gelu_f(float x) {
  const float a = x * x;
  const float b = fmaf(-0.10294538f, a, -2.3022077f);
  const float e = EXP2F(x * b);
  return x * __builtin_amdgcn_rcpf(1.f + e);
}

// Intra-wave LDS handoff: replaces __syncthreads in the wave-private design.
// DS ops may not cross (sched_barrier mask 0x7F allows ALU/SALU/VALU/MFMA/VMEM);
// lgkmcnt(0) drains this wave's LDS writes so all 64 lanes see them.
__device__ __forceinline__ void handoff() {
  __builtin_amdgcn_sched_barrier(0x7F);
  asm volatile("s_waitcnt lgkmcnt(0)" ::: "memory");
  __builtin_amdgcn_sched_barrier(0x7F);
}

// ---------------- weight convert + transpose to bf16 ----------------
// ws layout (u16): qwT[128*128] kwT vwT owT | ff1T[512*128] | ff2T[128*512]
__global__ void convert_w(const float* __restrict__ qw, const float* __restrict__ kw,
                          const float* __restrict__ vw, const float* __restrict__ ow,
                          const float* __restrict__ f1, const float* __restrict__ f2,
                          u16* __restrict__ o) {
  int i = blockIdx.x * 256 + threadIdx.x;
  if (i < 65536) {
    int which = i >> 14;
    const float* W = which == 0 ? qw : which == 1 ? kw : which == 2 ? vw : ow;
    int t = i & 16383;
    int n = t >> 7, k = t & 127;
    o[i] = f2bf(W[k * 128 + n]);
  } else if (i < 131072) {
    int t = i - 65536;
    int n = t >> 7, k = t & 127;
    o[i] = f2bf(f1[k * 512 + n]);
  } else if (i < 196608) {
    int t = i - 131072;
    int n = t >> 9, k = t & 511;
    o[i] = f2bf(f2[k * 128 + n]);
  }
}

// Per-wave GEMM: Y(12x(16c)) = A(12x128 wave-local LDS) @ W(128x16c), W transposed.
// arow = clamped lane16 (rows 12..15 duplicate row 11; their outputs are discarded).
// Lane(l16,kg) holds Y[xrow=l16][c*16 + kg*4 + r].
template <int NT>
__device__ __forceinline__ void wgemm(const u16* __restrict__ Abase,
                                      const u16* __restrict__ WT, int ldw,
                                      f32x4 acc[NT], int arow, int lane16, int kgrp) {
#pragma unroll
  for (int ks = 0; ks < 4; ++ks) {
    const int kk = ks * 32 + kgrp * 8;
    const bf16x8 a = *(const bf16x8*)(Abase + arow * LDA + kk);
    __builtin_amdgcn_s_setprio(1);
#pragma unroll
    for (int c = 0; c < NT; ++c) {
      const bf16x8 b = *(const bf16x8*)(WT + (c * 16 + lane16) * ldw + kk);
      acc[c] = MFMA32(b, a, acc[c]);
    }
    __builtin_amdgcn_s_setprio(0);
  }
}

__device__ __forceinline__ void wstore8(u16* __restrict__ dst /* row0 of wave region */,
                                        f32x4 acc[8], const float* __restrict__ bias,
                                        int lane16, int kgrp) {
  if (lane16 < 12) {
#pragma unroll
    for (int c = 0; c < 8; ++c) {
      const int col0 = c * 16 + kgrp * 4;
      const float4 bv = *(const float4*)(bias + col0);
      uint2 o;
      o.x = pk2bf(acc[c][0] + bv.x, acc[c][1] + bv.y);
      o.y = pk2bf(acc[c][2] + bv.z, acc[c][3] + bv.w);
      *(uint2*)(dst + lane16 * LDA + col0) = o;
    }
  }
}

__global__ __launch_bounds__(256, 4) void mitra_main(
    const float* __restrict__ x,
    const float* __restrict__ nw1, const float* __restrict__ nb1,
    const float* __restrict__ nw2, const float* __restrict__ nb2,
    const float* __restrict__ qb,  const float* __restrict__ kb,
    const float* __restrict__ vb,  const float* __restrict__ ob,
    const float* __restrict__ f1b, const float* __restrict__ f2b,
    const u16* __restrict__ wt, float* __restrict__ out) {
  __shared__ u16 XF[NROWS * LDA];   // xf -> xf2 (survives to epilogue)
  __shared__ u16 BA[NROWS * LDA];   // Q -> V -> H
  __shared__ u16 BB[NROWS * LDA];   // K -> O -> G (single buffer: wave-sequential)
  __shared__ u16 PS[4 * 144];       // per-wave softmax probs

  const int tid    = threadIdx.x;
  const int wave   = tid >> 6;
  const int lane   = tid & 63;
  const int lane16 = lane & 15;
  const int kgrp   = lane >> 4;
  const int R      = wave * 12;            // this wave's row base (2 slots x 6)
  const int arow   = lane16 < 12 ? lane16 : 11;
  u16* const XFw = XF + R * LDA;
  u16* const BAw = BA + R * LDA;
  u16* const BBw = BB + R * LDA;
  u16* const PSw = PS + wave * 144;
  const long slot0 = (long)blockIdx.x * SLOTS;

  // ---------- Phase 0: LN1(768) + LN2(128) -> XF (wave-local rows) ----------
  {
    const int s = tid >> 5, l32 = tid & 31;   // 32 lanes per slot, within wave
    const float* xr = x + (size_t)(slot0 + s) * 768;
    float4 v[6];
    float sm = 0.f, sq = 0.f;
#pragma unroll
    for (int i = 0; i < 6; ++i) {
      v[i] = *(const float4*)(xr + (l32 + 32 * i) * 4);
      sm += v[i].x + v[i].y + v[i].z + v[i].w;
      sq += v[i].x * v[i].x + v[i].y * v[i].y + v[i].z * v[i].z + v[i].w * v[i].w;
    }
#pragma unroll
    for (int m = 1; m < 32; m <<= 1) { sm += __shfl_xor(sm, m); sq += __shfl_xor(sq, m); }
    const float mu = sm * (1.f / 768.f);
    const float rs = rsqrtf(sq * (1.f / 768.f) - mu * mu + 1e-5f);
#pragma unroll
    for (int i = 0; i < 6; ++i) {
      const float4 w = *(const float4*)(nw1 + (l32 + 32 * i) * 4);
      const float4 b = *(const float4*)(nb1 + (l32 + 32 * i) * 4);
      v[i].x = (v[i].x - mu) * rs * w.x + b.x;
      v[i].y = (v[i].y - mu) * rs * w.y + b.y;
      v[i].z = (v[i].z - mu) * rs * w.z + b.z;
      v[i].w = (v[i].w - mu) * rs * w.w + b.w;
    }
    const float4 w2 = *(const float4*)(nw2 + l32 * 4);
    const float4 b2 = *(const float4*)(nb2 + l32 * 4);
#pragma unroll
    for (int i = 0; i < 6; ++i) {
      float s2 = v[i].x + v[i].y + v[i].z + v[i].w;
      float q2 = v[i].x * v[i].x + v[i].y * v[i].y + v[i].z * v[i].z + v[i].w * v[i].w;
#pragma unroll
      for (int m = 1; m < 32; m <<= 1) { s2 += __shfl_xor(s2, m); q2 += __shfl_xor(q2, m); }
      const float mu2 = s2 * (1.f / 128.f);
      const float rs2 = rsqrtf(q2 * (1.f / 128.f) - mu2 * mu2 + 1e-5f);
      const int row = s * 6 + i;    // within this wave's 12 rows
      uint2 o;
      o.x = pk2bf((v[i].x - mu2) * rs2 * w2.x + b2.x, (v[i].y - mu2) * rs2 * w2.y + b2.y);
      o.y = pk2bf((v[i].z - mu2) * rs2 * w2.z + b2.z, (v[i].w - mu2) * rs2 * w2.w + b2.w);
      *(uint2*)(XF + row * LDA + l32 * 4) = o;
    }
  }
  handoff();

  // ---------- Q -> BAw, K -> BBw ----------
  {
    f32x4 acc[8] = {};
    wgemm<8>(XFw, wt + 0, 128, acc, arow, lane16, kgrp);
    wstore8(BAw, acc, qb, lane16, kgrp);
  }
  {
    f32x4 acc[8] = {};
    wgemm<8>(XFw, wt + 16384, 128, acc, arow, lane16, kgrp);
    wstore8(BBw, acc, kb, lane16, kgrp);
  }
  handoff();

  // ---------- scores -> PSw ----------
  for (int si = lane; si < 144; si += 64) {
    const int slotl = si / 72;
    const int rem   = si % 72;
    const int h     = rem / 36;
    const int qi    = (rem % 36) / 6;
    const int ki    = rem % 6;
    const u32* qr = (const u32*)(BAw + (slotl * 6 + qi) * LDA + h * 64);
    const u32* kr = (const u32*)(BBw + (slotl * 6 + ki) * LDA + h * 64);
    float a = 0.f;
#pragma unroll
    for (int j = 0; j < 32; j += 2) {
      const uint2 qa = *(const uint2*)(qr + j);
      const uint2 ka = *(const uint2*)(kr + j);
      const float2 q0 = bf2x2(qa.x), q1 = bf2x2(qa.y);
      const float2 k0 = bf2x2(ka.x), k1 = bf2x2(ka.y);
      a = fmaf(q0.x, k0.x, fmaf(q0.y, k0.y, fmaf(q1.x, k1.x, fmaf(q1.y, k1.y, a))));
    }
    PSw[si] = f2bf(a * 0.125f);   // scale = 64^-0.5
  }
  handoff();

  // ---------- softmax (24 lanes) + V -> BAw (Q dead, scores done) ----------
  if (lane < 24) {
    u16* pr = PSw + lane * 6;
    float e[6];
    float m = bf2f(pr[0]);
#pragma unroll
    for (int k = 1; k < 6; ++k) m = fmaxf(m, bf2f(pr[k]));
    float ssum = 0.f;
#pragma unroll
    for (int k = 0; k < 6; ++k) { e[k] = EXP2F((bf2f(pr[k]) - m) * 1.44269504f); ssum += e[k]; }
    const float inv = __builtin_amdgcn_rcpf(ssum);
#pragma unroll
    for (int k = 0; k < 6; ++k) pr[k] = f2bf(e[k] * inv);
  }
  {
    f32x4 acc[8] = {};
    wgemm<8>(XFw, wt + 32768, 128, acc, arow, lane16, kgrp);
    wstore8(BAw, acc, vb, lane16, kgrp);
  }
  handoff();

  // ---------- O = P @ V -> BBw (K dead) ----------
  {
    const int d0 = (lane & 31) * 4;
    const int h  = d0 >> 6;
    const int rh = lane >> 5;           // slot_local
#pragma unroll
    for (int p = 0; p < 6; ++p) {
      const u16* pr = PSw + (rh * 2 + h) * 36 + p * 6;
      float o0 = 0, o1 = 0, o2 = 0, o3 = 0;
#pragma unroll
      for (int k = 0; k < 6; ++k) {
        const uint2 v2 = *(const uint2*)(BAw + (rh * 6 + k) * LDA + d0);
        const float pw = bf2f(pr[k]);
        const float2 a = bf2x2(v2.x), b = bf2x2(v2.y);
        o0 = fmaf(pw, a.x, o0); o1 = fmaf(pw, a.y, o1);
        o2 = fmaf(pw, b.x, o2); o3 = fmaf(pw, b.y, o3);
      }
      uint2 o; o.x = pk2bf(o0, o1); o.y = pk2bf(o2, o3);
      *(uint2*)(BBw + (rh * 6 + p) * LDA + d0) = o;
    }
  }
  handoff();

  // ---------- att_out = O @ ow + ob ; xf2 = xf + att_out -> XFw ----------
  {
    f32x4 acc[8] = {};
    wgemm<8>(BBw, wt + 49152, 128, acc, arow, lane16, kgrp);
    if (lane16 < 12) {
#pragma unroll
      for (int c = 0; c < 8; ++c) {
        const int col0 = c * 16 + kgrp * 4;
        const float4 bv = *(const float4*)(ob + col0);
        u16* px = XFw + lane16 * LDA + col0;
        const uint2 cur = *(const uint2*)px;
        const float2 lo = bf2x2(cur.x), hi = bf2x2(cur.y);
        uint2 o;
        o.x = pk2bf(lo.x + acc[c][0] + bv.x, lo.y + acc[c][1] + bv.y);
        o.y = pk2bf(hi.x + acc[c][2] + bv.z, hi.y + acc[c][3] + bv.w);
        *(uint2*)px = o;
      }
    }
  }
  handoff();

  // ---------- H = LN2(xf2) -> BAw (V dead) ----------
  {
    const int rh = lane >> 5, l32 = lane & 31;
    const float4 w2 = *(const float4*)(nw2 + l32 * 4);
    const float4 b2 = *(const float4*)(nb2 + l32 * 4);
#pragma unroll
    for (int i = 0; i < 6; ++i) {
      const int row = rh * 6 + i;
      const uint2 hv = *(const uint2*)(XFw + row * LDA + l32 * 4);
      const float2 lo = bf2x2(hv.x), hi = bf2x2(hv.y);
      float s2 = lo.x + lo.y + hi.x + hi.y;
      float q2 = lo.x * lo.x + lo.y * lo.y + hi.x * hi.x + hi.y * hi.y;
#pragma unroll
      for (int m = 1; m < 32; m <<= 1) { s2 += __shfl_xor(s2, m); q2 += __shfl_xor(q2, m); }
      const float mu2 = s2 * (1.f / 128.f);
      const float rs2 = rsqrtf(q2 * (1.f / 128.f) - mu2 * mu2 + 1e-5f);
      uint2 o;
      o.x = pk2bf((lo.x - mu2) * rs2 * w2.x + b2.x, (lo.y - mu2) * rs2 * w2.y + b2.y);
      o.y = pk2bf((hi.x - mu2) * rs2 * w2.z + b2.z, (hi.y - mu2) * rs2 * w2.w + b2.w);
      *(uint2*)(BAw + row * LDA + l32 * 4) = o;
    }
  }
  handoff();

  // ---------- FF: acc2 += gelu(H @ ff1_t + b) @ ff2_t, G in BBw (O dead) ----------
  // ff1 done in two 64-col halves (g[4]=16 regs) to keep live acc <= 48.
  f32x4 acc2[8] = {};
#pragma unroll
  for (int t = 0; t < 4; ++t) {
#pragma unroll
    for (int half = 0; half < 2; ++half) {
      f32x4 g[4] = {};
      wgemm<4>(BAw, wt + 65536 + (t * 128 + half * 64) * 128, 128, g, arow, lane16, kgrp);
      if (lane16 < 12) {
#pragma unroll
        for (int c = 0; c < 4; ++c) {
          const int col0 = half * 64 + c * 16 + kgrp * 4;
          const float4 bv = *(const float4*)(f1b + t * 128 + col0);
          uint2 o;
          o.x = pk2bf(gelu_f(g[c][0] + bv.x), gelu_f(g[c][1] + bv.y));
          o.y = pk2bf(gelu_f(g[c][2] + bv.z), gelu_f(g[c][3] + bv.w));
          *(uint2*)(BBw + lane16 * LDA + col0) = o;
        }
      }
    }
    handoff();
    // acc2 += G @ ff2_t   (A = BBw cols 0..127 = G_t, W rows = out cols, k off t*128)
#pragma unroll
    for (int ks = 0; ks < 4; ++ks) {
      const int kk = ks * 32 + kgrp * 8;
      const bf16x8 a = *(const bf16x8*)(BBw + arow * LDA + kk);
      __builtin_amdgcn_s_setprio(1);
#pragma unroll
      for (int c = 0; c < 8; ++c) {
        const bf16x8 b = *(const bf16x8*)(wt + 131072 + (c * 16 + lane16) * 512 + t * 128 + kk);
        acc2[c] = MFMA32(b, a, acc2[c]);
      }
      __builtin_amdgcn_s_setprio(0);
    }
    handoff();   // BBw reads drained before next t overwrites G
  }

  // ---------- out = x + xf2 + ff_out + ff2b ----------
  if (lane16 < 12) {
    const long gslot = slot0 + wave * 2 + lane16 / 6;
    const int  ch    = lane16 % 6;
#pragma unroll
    for (int c = 0; c < 8; ++c) {
      const int col0 = c * 16 + kgrp * 4;
      const float4 fb = *(const float4*)(f2b + col0);
      const size_t gi = (size_t)gslot * 768 + ch * 128 + col0;
      const float4 xv = *(const float4*)(x + gi);
      const uint2 xf2v = *(const uint2*)(XFw + lane16 * LDA + col0);
      const float2 lo = bf2x2(xf2v.x), hi = bf2x2(xf2v.y);
      float4 o;
      o.x = xv.x + lo.x + acc2[c][0] + fb.x;
      o.y = xv.y + lo.y + acc2[c][1] + fb.y;
      o.z = xv.z + hi.x + acc2[c][2] + fb.z;
      o.w = xv.w + hi.y + acc2[c][3] + fb.w;
      *(float4*)(out + gi) = o;
    }
  }
}

extern "C" void kernel_launch(void* const* d_in, const int* in_sizes, int n_in,
                              void* d_out, int out_size, void* d_ws, size_t ws_size,
                              hipStream_t stream) {
  const float* x   = (const float*)d_in[0];
  const float* nw1 = (const float*)d_in[1];
  const float* nb1 = (const float*)d_in[2];
  const float* nw2 = (const float*)d_in[3];
  const float* nb2 = (const float*)d_in[4];
  const float* qw  = (const float*)d_in[5];
  const float* qb  = (const float*)d_in[6];
  const float* kw  = (const float*)d_in[7];
  const float* kb  = (const float*)d_in[8];
  const float* vw  = (const float*)d_in[9];
  const float* vb  = (const float*)d_in[10];
  const float* ow  = (const float*)d_in[11];
  const float* ob  = (const float*)d_in[12];
  const float* f1w = (const float*)d_in[13];
  const float* f1b = (const float*)d_in[14];
  const float* f2w = (const float*)d_in[15];
  const float* f2b = (const float*)d_in[16];
  u16* wt = (u16*)d_ws;   // 196608 u16 = 384 KB

  convert_w<<<768, 256, 0, stream>>>(qw, kw, vw, ow, f1w, f2w, wt);

  const int M = in_sizes[0] / 768;   // 32768 slots
  mitra_main<<<M / SLOTS, 256, 0, stream>>>(x, nw1, nb1, nw2, nb2,
                                            qb, kb, vb, ob, f1b, f2b,
                                            wt, (float*)d_out);
}

// Round 12
// 223.068 us; speedup vs baseline: 3.3078x; 3.3078x over previous
//
#include <hip/hip_runtime.h>
#include <hip/hip_bf16.h>

typedef unsigned short u16;
typedef unsigned int u32;
using bf16x8 = __attribute__((ext_vector_type(8))) short;
using f32x4  = __attribute__((ext_vector_type(4))) float;

#define LDA   136   // 128 + 8 pad (16B-aligned rows, near-free bank aliasing)
#define SLOTS 8
#define NROWS 48    // SLOTS * 6

__device__ __forceinline__ u32 pk2bf(float a, float b) {
  u32 r;
  asm("v_cvt_pk_bf16_f32 %0, %1, %2" : "=v"(r) : "v"(a), "v"(b));
  return r;
}
__device__ __forceinline__ u16 f2bf(float f) { return (u16)pk2bf(f, f); }
__device__ __forceinline__ float bf2f(u16 h) {
  union { u32 u; float f; } v; v.u = ((u32)h) << 16;
  return v.f;
}
__device__ __forceinline__ float2 bf2x2(u32 u) {
  union { u32 u; float f; } a, b; a.u = u << 16; b.u = u & 0xffff0000u;
  return make_float2(a.f, b.f);
}

#if __has_builtin(__builtin_amdgcn_exp2f)
#define EXP2F(x) __builtin_amdgcn_exp2f(x)
#else
#define EXP2F(x) exp2f(x)
#endif

#define MFMA32(a, b, c) __builtin_amdgcn_mfma_f32_16x16x32_bf16(a, b, c, 0, 0, 0)

// tanh-form GELU (validated R3-R11: absmax stays 0.0625)
__device__ __forceinline__ float gelu_f(float x) {
  const float a = x * x;
  const float b = fmaf(-0.10294538f, a, -2.3022077f);
  const float e = EXP2F(x * b);
  return x * __builtin_amdgcn_rcpf(1.f + e);
}

// Intra-wave LDS handoff (no block barrier): DS ops may not cross; drain LDS.
__device__ __forceinline__ void handoff() {
  __builtin_amdgcn_sched_barrier(0x7F);
  asm volatile("s_waitcnt lgkmcnt(0)" ::: "memory");
  __builtin_amdgcn_sched_barrier(0x7F);
}

// ---------------- weight convert + transpose to bf16 ----------------
// ws layout (u16): qwT[128*128] kwT vwT owT | ff1T[512*128] | ff2T[128*512]
__global__ void convert_w(const float* __restrict__ qw, const float* __restrict__ kw,
                          const float* __restrict__ vw, const float* __restrict__ ow,
                          const float* __restrict__ f1, const float* __restrict__ f2,
                          u16* __restrict__ o) {
  int i = blockIdx.x * 256 + threadIdx.x;
  if (i < 65536) {
    int which = i >> 14;
    const float* W = which == 0 ? qw : which == 1 ? kw : which == 2 ? vw : ow;
    int t = i & 16383;
    int n = t >> 7, k = t & 127;
    o[i] = f2bf(W[k * 128 + n]);
  } else if (i < 131072) {
    int t = i - 65536;
    int n = t >> 7, k = t & 127;
    o[i] = f2bf(f1[k * 512 + n]);
  } else if (i < 196608) {
    int t = i - 131072;
    int n = t >> 9, k = t & 511;
    o[i] = f2bf(f2[k * 128 + n]);
  }
}

// mfma(F1,F2): lane(l16,kg) holds D[f2row=l16][f1row=kg*4+r]
// gemm48T: Y = A(48x128) @ W; WT rows as F1 -> lane holds Y[xrow=l16][4 consecutive wcols]
__device__ __forceinline__ void gemm48T(const u16* __restrict__ A, const u16* __restrict__ WT,
                                        int ldw, f32x4 acc[3][2],
                                        int wave, int lane16, int kgrp) {
#pragma unroll
  for (int ks = 0; ks < 4; ++ks) {
    const int kk = ks * 32 + kgrp * 8;
    bf16x8 a0 = *(const bf16x8*)(A + (0 * 16 + lane16) * LDA + kk);
    bf16x8 a1 = *(const bf16x8*)(A + (1 * 16 + lane16) * LDA + kk);
    bf16x8 a2 = *(const bf16x8*)(A + (2 * 16 + lane16) * LDA + kk);
    bf16x8 b0 = *(const bf16x8*)(WT + ((wave)     * 16 + lane16) * ldw + kk);
    bf16x8 b1 = *(const bf16x8*)(WT + ((wave + 4) * 16 + lane16) * ldw + kk);
    __builtin_amdgcn_s_setprio(1);
    acc[0][0] = MFMA32(b0, a0, acc[0][0]);
    acc[1][0] = MFMA32(b0, a1, acc[1][0]);
    acc[2][0] = MFMA32(b0, a2, acc[2][0]);
    acc[0][1] = MFMA32(b1, a0, acc[0][1]);
    acc[1][1] = MFMA32(b1, a1, acc[1][1]);
    acc[2][1] = MFMA32(b1, a2, acc[2][1]);
    __builtin_amdgcn_s_setprio(0);
  }
}

__device__ __forceinline__ void store48T(u16* __restrict__ dst, f32x4 acc[3][2],
                                         const float* __restrict__ bias,
                                         int wave, int lane16, int kgrp) {
#pragma unroll
  for (int c = 0; c < 2; ++c) {
    const int col0 = (wave + 4 * c) * 16 + kgrp * 4;
    const float4 bv = *(const float4*)(bias + col0);
#pragma unroll
    for (int xr = 0; xr < 3; ++xr) {
      uint2 o;
      o.x = pk2bf(acc[xr][c][0] + bv.x, acc[xr][c][1] + bv.y);
      o.y = pk2bf(acc[xr][c][2] + bv.z, acc[xr][c][3] + bv.w);
      *(uint2*)(dst + (xr * 16 + lane16) * LDA + col0) = o;
    }
  }
}

__global__ __launch_bounds__(256, 4) void mitra_main(
    const float* __restrict__ x,
    const float* __restrict__ nw1, const float* __restrict__ nb1,
    const float* __restrict__ nw2, const float* __restrict__ nb2,
    const float* __restrict__ qb,  const float* __restrict__ kb,
    const float* __restrict__ vb,  const float* __restrict__ ob,
    const float* __restrict__ f1b, const float* __restrict__ f2b,
    const u16* __restrict__ wt, float* __restrict__ out) {
  __shared__ u16 XF[NROWS * LDA];   // xf -> xf2 -> FF G ping buffer
  __shared__ u16 BA[NROWS * LDA];   // Q -> V -> H
  __shared__ u16 BB[NROWS * LDA];   // K -> O -> FF G pong buffer
  __shared__ u16 PS2[2 * 48 * 8];   // scores/probs bf16: [h][q][k-in-slot(6, pad 8)]

  const int tid    = threadIdx.x;
  const int wave   = tid >> 6;
  const int lane   = tid & 63;
  const int lane16 = lane & 15;
  const int kgrp   = lane >> 4;
  const long slot0 = (long)blockIdx.x * SLOTS;

  // ---------- Phase 0: LN1(768) + LN2(128) -> XF ----------
  {
    const int s = tid >> 5, l32 = tid & 31;
    const float* xr = x + (size_t)(slot0 + s) * 768;
    float4 v[6];
    float sm = 0.f, sq = 0.f;
#pragma unroll
    for (int i = 0; i < 6; ++i) {
      v[i] = *(const float4*)(xr + (l32 + 32 * i) * 4);
      sm += v[i].x + v[i].y + v[i].z + v[i].w;
      sq += v[i].x * v[i].x + v[i].y * v[i].y + v[i].z * v[i].z + v[i].w * v[i].w;
    }
#pragma unroll
    for (int m = 1; m < 32; m <<= 1) { sm += __shfl_xor(sm, m); sq += __shfl_xor(sq, m); }
    const float mu = sm * (1.f / 768.f);
    const float rs = rsqrtf(sq * (1.f / 768.f) - mu * mu + 1e-5f);
#pragma unroll
    for (int i = 0; i < 6; ++i) {
      const float4 w = *(const float4*)(nw1 + (l32 + 32 * i) * 4);
      const float4 b = *(const float4*)(nb1 + (l32 + 32 * i) * 4);
      v[i].x = (v[i].x - mu) * rs * w.x + b.x;
      v[i].y = (v[i].y - mu) * rs * w.y + b.y;
      v[i].z = (v[i].z - mu) * rs * w.z + b.z;
      v[i].w = (v[i].w - mu) * rs * w.w + b.w;
    }
    const float4 w2 = *(const float4*)(nw2 + l32 * 4);
    const float4 b2 = *(const float4*)(nb2 + l32 * 4);
#pragma unroll
    for (int i = 0; i < 6; ++i) {
      float s2 = v[i].x + v[i].y + v[i].z + v[i].w;
      float q2 = v[i].x * v[i].x + v[i].y * v[i].y + v[i].z * v[i].z + v[i].w * v[i].w;
#pragma unroll
      for (int m = 1; m < 32; m <<= 1) { s2 += __shfl_xor(s2, m); q2 += __shfl_xor(q2, m); }
      const float mu2 = s2 * (1.f / 128.f);
      const float rs2 = rsqrtf(q2 * (1.f / 128.f) - mu2 * mu2 + 1e-5f);
      const int row = s * 6 + i;
      uint2 o;
      o.x = pk2bf((v[i].x - mu2) * rs2 * w2.x + b2.x, (v[i].y - mu2) * rs2 * w2.y + b2.y);
      o.y = pk2bf((v[i].z - mu2) * rs2 * w2.z + b2.z, (v[i].w - mu2) * rs2 * w2.w + b2.w);
      *(uint2*)(XF + row * LDA + l32 * 4) = o;
    }
  }
  __syncthreads();

  // ---------- Q -> BA, K -> BB ----------
  {
    f32x4 acc[3][2] = {};
    gemm48T(XF, wt + 0, 128, acc, wave, lane16, kgrp);
    store48T(BA, acc, qb, wave, lane16, kgrp);
  }
  {
    f32x4 acc[3][2] = {};
    gemm48T(XF, wt + 16384, 128, acc, wave, lane16, kgrp);
    store48T(BB, acc, kb, wave, lane16, kgrp);
  }
  __syncthreads();

  // ---------- scores via MFMA: 14 jobs (7 diag tiles x 2 heads) over 4 waves ----------
  // mfma(K_rows, Q_rows): lane(l16,kg) holds S[q = qt*16+l16][k = kt*16+kg*4+r]
  {
#pragma unroll
    for (int jl = 0; jl < 4; ++jl) {
      const int j = wave + jl * 4;
      if (j < 14) {
        const int h = j & 1;
        const int t = j >> 1;                       // 0..6
        const int qt = (t >= 2) + (t >= 5);
        const int kt = t - 2 * qt;
        f32x4 acc = {};
#pragma unroll
        for (int ks = 0; ks < 2; ++ks) {
          const int kk = h * 64 + ks * 32 + kgrp * 8;
          const bf16x8 kf = *(const bf16x8*)(BB + (kt * 16 + lane16) * LDA + kk);
          const bf16x8 qf = *(const bf16x8*)(BA + (qt * 16 + lane16) * LDA + kk);
          acc = MFMA32(kf, qf, acc);
        }
        const int q    = qt * 16 + lane16;
        const int klo  = 6 * ((unsigned)q / 6u);
        u16* pq = PS2 + (h * 48 + q) * 8;
#pragma unroll
        for (int r = 0; r < 4; ++r) {
          const int off = kt * 16 + kgrp * 4 + r - klo;
          if ((unsigned)off < 6u) pq[off] = f2bf(acc[r] * 0.125f);
        }
      }
    }
  }
  __syncthreads();

  // ---------- V -> BA (Q dead) ----------
  {
    f32x4 acc[3][2] = {};
    gemm48T(XF, wt + 32768, 128, acc, wave, lane16, kgrp);
    store48T(BA, acc, vb, wave, lane16, kgrp);
  }
  __syncthreads();

  // ---------- softmax (wave-local rows) + O = P @ V -> BB rows 12w.. (K dead) ----------
  {
    // softmax: wave w owns q rows 12w..12w+11, both heads (24 rows)
    if (lane < 24) {
      const int h  = lane / 12;
      const int q  = wave * 12 + (lane % 12);
      u16* pr = PS2 + (h * 48 + q) * 8;
      float e[6];
      float m = bf2f(pr[0]);
#pragma unroll
      for (int k = 1; k < 6; ++k) m = fmaxf(m, bf2f(pr[k]));
      float ssum = 0.f;
#pragma unroll
      for (int k = 0; k < 6; ++k) { e[k] = EXP2F((bf2f(pr[k]) - m) * 1.44269504f); ssum += e[k]; }
      const float inv = __builtin_amdgcn_rcpf(ssum);
#pragma unroll
      for (int k = 0; k < 6; ++k) pr[k] = f2bf(e[k] * inv);
    }
    handoff();   // intra-wave: PV below reads this wave's PS2 rows

    // PV: wave w computes O rows 12w..12w+11, all 128 cols.
    // lane: dseg = lane&15 (8 cols each), rgrp = lane>>4 (3 rows each)
    const int dseg = lane & 15;
    const int d0   = dseg * 8;
    const int h    = dseg >> 3;
    const int rgrp = lane >> 4;
#pragma unroll
    for (int p = 0; p < 3; ++p) {
      const int rl = rgrp * 3 + p;          // 0..11
      const int q  = wave * 12 + rl;
      const int sl = rl / 6;
      const u16* pr = PS2 + (h * 48 + q) * 8;
      const u16* vbase = BA + (wave * 12 + sl * 6) * LDA + d0;
      float o0 = 0, o1 = 0, o2 = 0, o3 = 0, o4 = 0, o5 = 0, o6 = 0, o7 = 0;
#pragma unroll
      for (int k = 0; k < 6; ++k) {
        const uint4 v4 = *(const uint4*)(vbase + k * LDA);
        const float pw = bf2f(pr[k]);
        const float2 a = bf2x2(v4.x), b = bf2x2(v4.y);
        const float2 c = bf2x2(v4.z), d = bf2x2(v4.w);
        o0 = fmaf(pw, a.x, o0); o1 = fmaf(pw, a.y, o1);
        o2 = fmaf(pw, b.x, o2); o3 = fmaf(pw, b.y, o3);
        o4 = fmaf(pw, c.x, o4); o5 = fmaf(pw, c.y, o5);
        o6 = fmaf(pw, d.x, o6); o7 = fmaf(pw, d.y, o7);
      }
      uint4 o;
      o.x = pk2bf(o0, o1); o.y = pk2bf(o2, o3);
      o.z = pk2bf(o4, o5); o.w = pk2bf(o6, o7);
      *(uint4*)(BB + q * LDA + d0) = o;
    }
  }
  __syncthreads();

  // ---------- att_out = O @ ow + ob ; xf2 = xf + att_out -> XF ----------
  {
    f32x4 acc[3][2] = {};
    gemm48T(BB, wt + 49152, 128, acc, wave, lane16, kgrp);
#pragma unroll
    for (int c = 0; c < 2; ++c) {
      const int col0 = (wave + 4 * c) * 16 + kgrp * 4;
      const float4 bv = *(const float4*)(ob + col0);
#pragma unroll
      for (int xr = 0; xr < 3; ++xr) {
        u16* px = XF + (xr * 16 + lane16) * LDA + col0;
        const uint2 cur = *(const uint2*)px;
        const float2 lo = bf2x2(cur.x), hi = bf2x2(cur.y);
        uint2 o;
        o.x = pk2bf(lo.x + acc[xr][c][0] + bv.x, lo.y + acc[xr][c][1] + bv.y);
        o.y = pk2bf(hi.x + acc[xr][c][2] + bv.z, hi.y + acc[xr][c][3] + bv.w);
        *(uint2*)px = o;
      }
    }
  }
  __syncthreads();

  // ---------- H = LN2(xf2) -> BA (V dead) ----------
  {
    const int g = tid >> 5, l32 = tid & 31;
    const float4 w2 = *(const float4*)(nw2 + l32 * 4);
    const float4 b2 = *(const float4*)(nb2 + l32 * 4);
#pragma unroll
    for (int i = 0; i < 6; ++i) {
      const int row = g * 6 + i;
      const uint2 hv = *(const uint2*)(XF + row * LDA + l32 * 4);
      const float2 lo = bf2x2(hv.x), hi = bf2x2(hv.y);
      float s2 = lo.x + lo.y + hi.x + hi.y;
      float q2 = lo.x * lo.x + lo.y * lo.y + hi.x * hi.x + hi.y * hi.y;
#pragma unroll
      for (int m = 1; m < 32; m <<= 1) { s2 += __shfl_xor(s2, m); q2 += __shfl_xor(q2, m); }
      const float mu2 = s2 * (1.f / 128.f);
      const float rs2 = rsqrtf(q2 * (1.f / 128.f) - mu2 * mu2 + 1e-5f);
      uint2 o;
      o.x = pk2bf((lo.x - mu2) * rs2 * w2.x + b2.x, (lo.y - mu2) * rs2 * w2.y + b2.y);
      o.y = pk2bf((hi.x - mu2) * rs2 * w2.z + b2.z, (hi.y - mu2) * rs2 * w2.w + b2.w);
      *(uint2*)(BA + row * LDA + l32 * 4) = o;
    }
  }

  // ---------- preload acc2 with xf2 (frees XF as an FF G buffer) ----------
  f32x4 acc2[3][2];
#pragma unroll
  for (int c = 0; c < 2; ++c) {
    const int col0 = (wave + 4 * c) * 16 + kgrp * 4;
#pragma unroll
    for (int xr = 0; xr < 3; ++xr) {
      const uint2 t2 = *(const uint2*)(XF + (xr * 16 + lane16) * LDA + col0);
      const float2 lo = bf2x2(t2.x), hi = bf2x2(t2.y);
      acc2[xr][c][0] = lo.x; acc2[xr][c][1] = lo.y;
      acc2[xr][c][2] = hi.x; acc2[xr][c][3] = hi.y;
    }
  }
  __syncthreads();

  // ---------- FF with G ping-pong {BB, XF}: one barrier per t ----------
  {
    f32x4 g[3][2] = {};
    gemm48T(BA, wt + 65536, 128, g, wave, lane16, kgrp);
#pragma unroll
    for (int c = 0; c < 2; ++c) {
      const int col0 = (wave + 4 * c) * 16 + kgrp * 4;
      const float4 bv = *(const float4*)(f1b + col0);
#pragma unroll
      for (int xr = 0; xr < 3; ++xr) {
        uint2 o;
        o.x = pk2bf(gelu_f(g[xr][c][0] + bv.x), gelu_f(g[xr][c][1] + bv.y));
        o.y = pk2bf(gelu_f(g[xr][c][2] + bv.z), gelu_f(g[xr][c][3] + bv.w));
        *(uint2*)(BB + (xr * 16 + lane16) * LDA + col0) = o;
      }
    }
  }
  __syncthreads();
#pragma unroll
  for (int t = 1; t < 4; ++t) {
    u16* const Gprev = (t & 1) ? BB : XF;
    u16* const Gcur  = (t & 1) ? XF : BB;
    gemm48T(Gprev, wt + 131072 + (t - 1) * 128, 512, acc2, wave, lane16, kgrp);
    f32x4 g[3][2] = {};
    gemm48T(BA, wt + 65536 + t * 16384, 128, g, wave, lane16, kgrp);
#pragma unroll
    for (int c = 0; c < 2; ++c) {
      const int col0 = (wave + 4 * c) * 16 + kgrp * 4;
      const float4 bv = *(const float4*)(f1b + t * 128 + col0);
#pragma unroll
      for (int xr = 0; xr < 3; ++xr) {
        uint2 o;
        o.x = pk2bf(gelu_f(g[xr][c][0] + bv.x), gelu_f(g[xr][c][1] + bv.y));
        o.y = pk2bf(gelu_f(g[xr][c][2] + bv.z), gelu_f(g[xr][c][3] + bv.w));
        *(uint2*)(Gcur + (xr * 16 + lane16) * LDA + col0) = o;
      }
    }
    __syncthreads();
  }
  gemm48T(XF, wt + 131072 + 3 * 128, 512, acc2, wave, lane16, kgrp);

  // ---------- out = x + (xf2 + ff_out) + ff2b  (acc2 already holds xf2) ----------
#pragma unroll
  for (int c = 0; c < 2; ++c) {
    const int col0 = (wave + 4 * c) * 16 + kgrp * 4;
    const float4 fb = *(const float4*)(f2b + col0);
#pragma unroll
    for (int xr = 0; xr < 3; ++xr) {
      const int row  = xr * 16 + lane16;
      const int slot = row / 6, ch = row % 6;
      const size_t gi = (size_t)(slot0 + slot) * 768 + ch * 128 + col0;
      const float4 xv = *(const float4*)(x + gi);
      float4 o;
      o.x = xv.x + acc2[xr][c][0] + fb.x;
      o.y = xv.y + acc2[xr][c][1] + fb.y;
      o.z = xv.z + acc2[xr][c][2] + fb.z;
      o.w = xv.w + acc2[xr][c][3] + fb.w;
      *(float4*)(out + gi) = o;
    }
  }
}

extern "C" void kernel_launch(void* const* d_in, const int* in_sizes, int n_in,
                              void* d_out, int out_size, void* d_ws, size_t ws_size,
                              hipStream_t stream) {
  const float* x   = (const float*)d_in[0];
  const float* nw1 = (const float*)d_in[1];
  const float* nb1 = (const float*)d_in[2];
  const float* nw2 = (const float*)d_in[3];
  const float* nb2 = (const float*)d_in[4];
  const float* qw  = (const float*)d_in[5];
  const float* qb  = (const float*)d_in[6];
  const float* kw  = (const float*)d_in[7];
  const float* kb  = (const float*)d_in[8];
  const float* vw  = (const float*)d_in[9];
  const float* vb  = (const float*)d_in[10];
  const float* ow  = (const float*)d_in[11];
  const float* ob  = (const float*)d_in[12];
  const float* f1w = (const float*)d_in[13];
  const float* f1b = (const float*)d_in[14];
  const float* f2w = (const float*)d_in[15];
  const float* f2b = (const float*)d_in[16];
  u16* wt = (u16*)d_ws;   // 196608 u16 = 384 KB

  convert_w<<<768, 256, 0, stream>>>(qw, kw, vw, ow, f1w, f2w, wt);

  const int M = in_sizes[0] / 768;   // 32768 slots
  mitra_main<<<M / SLOTS, 256, 0, stream>>>(x, nw1, nb1, nw2, nb2,
                                            qb, kb, vb, ob, f1b, f2b,
                                            wt, (float*)d_out);
}